// Round 8
// baseline (303.204 us; speedup 1.0000x reference)
//
#include <hip/hip_runtime.h>
#include <hip/hip_bf16.h>
#include <cstddef>
#include <cstdint>

#define B_   2
#define S_   2048
#define H_   2048
#define NH_  32
#define NKV_ 8
#define HD_  64

typedef __attribute__((ext_vector_type(8))) short short8;
typedef __attribute__((ext_vector_type(4))) float v4f;
typedef __attribute__((ext_vector_type(16))) float v16f;

#define MAXC 48.0f
#define QSCALE 0.18033688011112042f   /* 0.125 * log2(e) */

__device__ __forceinline__ unsigned short f2b(float f) {
    unsigned int u = __float_as_uint(f);
    u += 0x7FFFu + ((u >> 16) & 1u);
    return (unsigned short)(u >> 16);
}
__device__ __forceinline__ unsigned int pkbf(float a, float b) {
    __hip_bfloat162 h = __float22bfloat162_rn(float2{a, b});
    return *(unsigned int*)&h;
}
__device__ __forceinline__ float fexp2(float x) {
#if __has_builtin(__builtin_amdgcn_exp2f)
    return __builtin_amdgcn_exp2f(x);      // raw v_exp_f32; inputs in [-96, 0]
#else
    return exp2f(x);
#endif
}
__device__ __forceinline__ v4f mfma16(short8 a, short8 b, v4f c) {
    return __builtin_amdgcn_mfma_f32_16x16x32_bf16(a, b, c, 0, 0, 0);
}
__device__ __forceinline__ v16f mfma32(short8 a, short8 b, v16f c) {
    return __builtin_amdgcn_mfma_f32_32x32x16_bf16(a, b, c, 0, 0, 0);
}
__device__ __forceinline__ void gll16(void* lds, const void* g) {
    __builtin_amdgcn_global_load_lds(
        (const __attribute__((address_space(1))) unsigned int*)g,
        (__attribute__((address_space(3))) unsigned int*)lds, 16, 0, 0);
}

// ---------------------------------------------------------------------------
// fp32 -> bf16 conversion for x, Wq, Wk, Wv, Wo
// ---------------------------------------------------------------------------
__global__ __launch_bounds__(256) void convert_all(
    const float* __restrict__ x, const float* __restrict__ wq,
    const float* __restrict__ wk, const float* __restrict__ wv,
    const float* __restrict__ wo,
    unsigned short* __restrict__ xb, unsigned short* __restrict__ wqb,
    unsigned short* __restrict__ wkb, unsigned short* __restrict__ wvb,
    unsigned short* __restrict__ wob)
{
    size_t i = ((size_t)blockIdx.x * 256 + threadIdx.x) * 4;
    const float* src; unsigned short* dst; size_t off;
    if (i < 8388608)       { src = x;  dst = xb;  off = i; }
    else if (i < 12582912) { src = wq; dst = wqb; off = i - 8388608; }
    else if (i < 13631488) { src = wk; dst = wkb; off = i - 12582912; }
    else if (i < 14680064) { src = wv; dst = wvb; off = i - 13631488; }
    else                   { src = wo; dst = wob; off = i - 14680064; }
    float4 v = *(const float4*)(src + off);
    ushort4 o;
    o.x = f2b(v.x); o.y = f2b(v.y); o.z = f2b(v.z); o.w = f2b(v.w);
    *(ushort4*)(dst + off) = o;
}

// ---------------------------------------------------------------------------
// R8 qkv GEMM: BM=BN=256, BK=64, 512 thr / 8 waves (2M x 4N), wave-tile
// 128x64 (acc[8][4]) — the m201 intensity geometry: 28 ds_read_b128 per
// 64 MFMA/wave/K-tile (0.375 KB/MFMA vs R7's 0.5) lifts the LDS-BW-bound
// local ceiling ~45% -> ~62%. 2-buffer LDS 128KB (1 blk/CU).
// Per K-tile: 4 phases x 16 MFMA, quadrant order m0n0 -> m0n1 -> m1n1 ->
// m1n0 (af reload at ph0/ph2: 8 reads; bf at ph0/ph1/ph3: 4) and 2 gll16
// lines of tile t+1 per phase -> at the tile-top vmcnt(0) gate every load
// is >=3 phases old (L2-resident sources), so the drain is cheap.
// Raw s_barrier + sched_barrier(0) pacing; setprio(1) around MFMA.
// Swizzle unchanged (proven 0-conflict): LDS slot c of row r = chunk
// c^(r&7); read slot ((kk*4+quad)^(tx&7))*8.
// Grid 192 = 16M x 12N (XCD-bijective 8x24): bj 0-7 Q (RoPE+QSCALE),
// 8-9 K (RoPE), 10-11 V (transposed Vt[d][m]). Epilogue = R6's verified
// acc[8][4] code verbatim.
// ---------------------------------------------------------------------------
__global__ __launch_bounds__(512, 2) void qkv_gemm(
    const unsigned short* __restrict__ xb,
    const unsigned short* __restrict__ wqb, const unsigned short* __restrict__ wkb,
    const unsigned short* __restrict__ wvb,
    const float* __restrict__ bq, const float* __restrict__ bk,
    const float* __restrict__ bv,
    const float* __restrict__ fc, const float* __restrict__ fs,
    unsigned short* __restrict__ Qb, unsigned short* __restrict__ Kb,
    unsigned short* __restrict__ Vt)
{
    __shared__ unsigned short As[2][256 * 64];
    __shared__ unsigned short Bs[2][256 * 64];
    const int tid = threadIdx.x;
    const int lane = tid & 63, w = tid >> 6;       // 8 waves
    const int tx = lane & 15, quad = lane >> 4;

    const int bid = blockIdx.x;                    // 192 = 8 XCD x 24
    const int swz = (bid & 7) * 24 + (bid >> 3);
    const int bi = swz / 12, bj = swz % 12;
    const int bm = bi * 256;

    const unsigned short* Bp; int mode, nbase;
    if (bj < 8)       { Bp = wqb + (size_t)(bj * 256) * 2048;        mode = 0; nbase = bj * 256; }
    else if (bj < 10) { Bp = wkb + (size_t)((bj - 8) * 256) * 2048;  mode = 1; nbase = (bj - 8) * 256; }
    else              { Bp = wvb + (size_t)((bj - 10) * 256) * 2048; mode = 2; nbase = (bj - 10) * 256; }
    const unsigned short* Ap = xb + (size_t)bm * 2048;

    const int wm = (w >> 2) * 128, wn = (w & 3) * 64;

    v4f acc[8][4];
#pragma unroll
    for (int i = 0; i < 8; ++i)
#pragma unroll
        for (int j = 0; j < 4; ++j) acc[i][j] = (v4f)0.f;

    // staging: wave w stages rows [w*32, w*32+32) per line-group; lane ->
    // row i*8+(lane>>3), global chunk (lane&7)^(lane>>3) of the 64-elem slab
    const int r8 = lane >> 3, gc = (lane & 7) ^ r8;
    const unsigned short* ga = Ap + (size_t)(w * 32 + r8) * 2048 + gc * 8;
    const unsigned short* gb = Bp + (size_t)(w * 32 + r8) * 2048 + gc * 8;

#define SA(c, i, t) gll16(&As[c][(w * 32 + (i) * 8) * 64], \
                          ga + (size_t)((i) * 8) * 2048 + (size_t)(t) * 64);
#define SB(c, i, t) gll16(&Bs[c][(w * 32 + (i) * 8) * 64], \
                          gb + (size_t)((i) * 8) * 2048 + (size_t)(t) * 64);

    // frag-read slots (loop-invariant): chunk kk*4+quad XOR (row&7 = tx&7)
    const int t7 = tx & 7;
    int sl[2];
#pragma unroll
    for (int kk = 0; kk < 2; ++kk) sl[kk] = ((kk * 4 + quad) ^ t7) * 8;

    // prologue: tile 0 -> buf0
    SA(0, 0, 0) SA(0, 1, 0) SA(0, 2, 0) SA(0, 3, 0)
    SB(0, 0, 0) SB(0, 1, 0) SB(0, 2, 0) SB(0, 3, 0)

    short8 af[4][2], bf[2][2];

    for (int t = 0; t < 32; ++t) {
        const int cur = t & 1, nxt = cur ^ 1;
        asm volatile("s_waitcnt vmcnt(0)" ::: "memory");
        __builtin_amdgcn_sched_barrier(0);
        __builtin_amdgcn_s_barrier();              // tile t resident; buf nxt free
        __builtin_amdgcn_sched_barrier(0);
        const unsigned short* Asb = As[cur];
        const unsigned short* Bsb = Bs[cur];
        const bool pf = (t < 31);

        // ---- ph0: quadrant m0 x n01 ; stage A lines 0,1 of t+1 ----
#pragma unroll
        for (int mt = 0; mt < 4; ++mt)
#pragma unroll
            for (int kk = 0; kk < 2; ++kk)
                af[mt][kk] = *(const short8*)&Asb[(wm + mt * 16 + tx) * 64 + sl[kk]];
#pragma unroll
        for (int nt = 0; nt < 2; ++nt)
#pragma unroll
            for (int kk = 0; kk < 2; ++kk)
                bf[nt][kk] = *(const short8*)&Bsb[(wn + nt * 16 + tx) * 64 + sl[kk]];
        if (pf) { SA(nxt, 0, t + 1) SA(nxt, 1, t + 1) }
        __builtin_amdgcn_s_setprio(1);
#pragma unroll
        for (int kk = 0; kk < 2; ++kk)
#pragma unroll
            for (int mt = 0; mt < 4; ++mt)
#pragma unroll
                for (int nt = 0; nt < 2; ++nt)
                    acc[mt][nt] = mfma16(af[mt][kk], bf[nt][kk], acc[mt][nt]);
        __builtin_amdgcn_s_setprio(0);
        __builtin_amdgcn_sched_barrier(0);
        __builtin_amdgcn_s_barrier();
        __builtin_amdgcn_sched_barrier(0);

        // ---- ph1: quadrant m0 x n23 ; stage A lines 2,3 ----
#pragma unroll
        for (int nt = 0; nt < 2; ++nt)
#pragma unroll
            for (int kk = 0; kk < 2; ++kk)
                bf[nt][kk] = *(const short8*)&Bsb[(wn + (nt + 2) * 16 + tx) * 64 + sl[kk]];
        if (pf) { SA(nxt, 2, t + 1) SA(nxt, 3, t + 1) }
        __builtin_amdgcn_s_setprio(1);
#pragma unroll
        for (int kk = 0; kk < 2; ++kk)
#pragma unroll
            for (int mt = 0; mt < 4; ++mt)
#pragma unroll
                for (int nt = 0; nt < 2; ++nt)
                    acc[mt][nt + 2] = mfma16(af[mt][kk], bf[nt][kk], acc[mt][nt + 2]);
        __builtin_amdgcn_s_setprio(0);
        __builtin_amdgcn_sched_barrier(0);
        __builtin_amdgcn_s_barrier();
        __builtin_amdgcn_sched_barrier(0);

        // ---- ph2: quadrant m1 x n23 (reuse bf) ; stage B lines 0,1 ----
#pragma unroll
        for (int mt = 0; mt < 4; ++mt)
#pragma unroll
            for (int kk = 0; kk < 2; ++kk)
                af[mt][kk] = *(const short8*)&Asb[(wm + 64 + mt * 16 + tx) * 64 + sl[kk]];
        if (pf) { SB(nxt, 0, t + 1) SB(nxt, 1, t + 1) }
        __builtin_amdgcn_s_setprio(1);
#pragma unroll
        for (int kk = 0; kk < 2; ++kk)
#pragma unroll
            for (int mt = 0; mt < 4; ++mt)
#pragma unroll
                for (int nt = 0; nt < 2; ++nt)
                    acc[mt + 4][nt + 2] = mfma16(af[mt][kk], bf[nt][kk], acc[mt + 4][nt + 2]);
        __builtin_amdgcn_s_setprio(0);
        __builtin_amdgcn_sched_barrier(0);
        __builtin_amdgcn_s_barrier();
        __builtin_amdgcn_sched_barrier(0);

        // ---- ph3: quadrant m1 x n01 ; stage B lines 2,3 ----
#pragma unroll
        for (int nt = 0; nt < 2; ++nt)
#pragma unroll
            for (int kk = 0; kk < 2; ++kk)
                bf[nt][kk] = *(const short8*)&Bsb[(wn + nt * 16 + tx) * 64 + sl[kk]];
        if (pf) { SB(nxt, 2, t + 1) SB(nxt, 3, t + 1) }
        __builtin_amdgcn_s_setprio(1);
#pragma unroll
        for (int kk = 0; kk < 2; ++kk)
#pragma unroll
            for (int mt = 0; mt < 4; ++mt)
#pragma unroll
                for (int nt = 0; nt < 2; ++nt)
                    acc[mt + 4][nt] = mfma16(af[mt][kk], bf[nt][kk], acc[mt + 4][nt]);
        __builtin_amdgcn_s_setprio(0);
        // no trailing barrier: next tile's top barrier orders buffer reuse
    }
#undef SA
#undef SB

    if (mode <= 1) {
        unsigned short* Cout = mode ? Kb : Qb;
        const float* bias    = mode ? bk : bq;
        const int ldN        = mode ? 512 : 2048;
        const float scq      = mode ? 1.0f : QSCALE;
        float bx0 = bias[nbase + wn +  0 + tx];
        float bx1 = bias[nbase + wn + 16 + tx];
        float bx2 = bias[nbase + wn + 32 + tx];
        float bx3 = bias[nbase + wn + 48 + tx];
#pragma unroll
        for (int mt = 0; mt < 8; ++mt)
#pragma unroll
            for (int rg = 0; rg < 4; ++rg) {
                int m = bm + wm + mt * 16 + quad * 4 + rg;
                int s = m & (S_ - 1);
                float c0 = fc[s * 32 + tx],      c1 = fc[s * 32 + 16 + tx];
                float s0 = fs[s * 32 + tx],      s1 = fs[s * 32 + 16 + tx];
                float q0 = acc[mt][0][rg] + bx0, q1 = acc[mt][1][rg] + bx1;
                float q2 = acc[mt][2][rg] + bx2, q3 = acc[mt][3][rg] + bx3;
                size_t base = (size_t)m * ldN + nbase + wn + tx;
                Cout[base]      = f2b((q0 * c0 - q2 * s0) * scq);
                Cout[base + 16] = f2b((q1 * c1 - q3 * s1) * scq);
                Cout[base + 32] = f2b((q2 * c0 + q0 * s0) * scq);
                Cout[base + 48] = f2b((q3 * c1 + q1 * s1) * scq);
            }
    } else {
        // V: acc[m][d] -> Vt[d * 4096 + m] (m = b*2048 + s), 8B stores
#pragma unroll
        for (int nt = 0; nt < 4; ++nt) {
            int d = nbase + wn + nt * 16 + tx;
            float bvv = bv[d];
#pragma unroll
            for (int mt = 0; mt < 8; ++mt) {
                int m0 = bm + wm + mt * 16 + quad * 4;
                ushort4 o;
                o.x = f2b(acc[mt][nt][0] + bvv);
                o.y = f2b(acc[mt][nt][1] + bvv);
                o.z = f2b(acc[mt][nt][2] + bvv);
                o.w = f2b(acc[mt][nt][3] + bvv);
                *(ushort4*)&Vt[(size_t)d * 4096 + m0] = o;
            }
        }
    }
}

// staging helpers for out_gemm (R7 template)
#define STG_A(c, i, t) gll16(&As[c][(w * 32 + (i) * 8) * 64], \
                             ga + (size_t)((i) * 8) * 2048 + (size_t)(t) * 64);
#define STG_B(c, i, t) gll16(&Bs[c][(w * 16 + (i) * 8) * 64], \
                             gb + (size_t)((i) * 8) * 2048 + (size_t)(t) * 64);

// ---------------------------------------------------------------------------
// Output GEMM — R7 template unchanged (exact 256-block fill).
// ---------------------------------------------------------------------------
__global__ __launch_bounds__(512, 2) void out_gemm(
    const unsigned short* __restrict__ Ab, const unsigned short* __restrict__ Bw,
    float* __restrict__ C)
{
    __shared__ unsigned short As[3][256 * 64];
    __shared__ unsigned short Bs[3][128 * 64];
    const int tid = threadIdx.x;
    const int lane = tid & 63, w = tid >> 6;
    const int tx = lane & 15, quad = lane >> 4;

    const int bid = blockIdx.x;                    // 256 = 8 XCD x 32
    const int swz = (bid & 7) * 32 + (bid >> 3);
    const int bm = (swz >> 4) * 256, bn = (swz & 15) * 128;

    const int wm = (w >> 1) * 64, wn = (w & 1) * 64;

    v4f acc[4][4];
#pragma unroll
    for (int i = 0; i < 4; ++i)
#pragma unroll
        for (int j = 0; j < 4; ++j) acc[i][j] = (v4f)0.f;

    const int r8 = lane >> 3, gc = (lane & 7) ^ r8;
    const unsigned short* ga = Ab + (size_t)(bm + w * 32 + r8) * 2048 + gc * 8;
    const unsigned short* gb = Bw + (size_t)(bn + w * 16 + r8) * 2048 + gc * 8;

    const int t7 = tx & 7;
    int sl[2];
#pragma unroll
    for (int kk = 0; kk < 2; ++kk) sl[kk] = ((kk * 4 + quad) ^ t7) * 8;

    STG_A(0, 0, 0) STG_A(0, 1, 0) STG_B(0, 0, 0)
    STG_A(0, 2, 0) STG_A(0, 3, 0) STG_B(0, 1, 0)
    STG_A(1, 0, 1) STG_A(1, 1, 1) STG_B(1, 0, 1)
    STG_A(1, 2, 1) STG_A(1, 3, 1) STG_B(1, 1, 1)

    int cb = 0;
    for (int t = 0; t < 32; ++t) {
        if (t < 31) asm volatile("s_waitcnt vmcnt(6)" ::: "memory");
        else        asm volatile("s_waitcnt vmcnt(0)" ::: "memory");
        __builtin_amdgcn_sched_barrier(0);
        __builtin_amdgcn_s_barrier();
        __builtin_amdgcn_sched_barrier(0);

        const unsigned short* Asb = As[cb];
        const unsigned short* Bsb = Bs[cb];
        const int nb = (cb == 0) ? 2 : cb - 1;
        const bool pf = (t < 30);

        short8 af[4][2], bf[2][2];
#pragma unroll
        for (int mt = 0; mt < 4; ++mt)
#pragma unroll
            for (int kk = 0; kk < 2; ++kk)
                af[mt][kk] = *(const short8*)&Asb[(wm + mt * 16 + tx) * 64 + sl[kk]];
#pragma unroll
        for (int nt = 0; nt < 2; ++nt)
#pragma unroll
            for (int kk = 0; kk < 2; ++kk)
                bf[nt][kk] = *(const short8*)&Bsb[(wn + nt * 16 + tx) * 64 + sl[kk]];
        if (pf) { STG_A(nb, 0, t + 2) STG_A(nb, 1, t + 2) STG_B(nb, 0, t + 2) }
        __builtin_amdgcn_s_setprio(1);
#pragma unroll
        for (int kk = 0; kk < 2; ++kk)
#pragma unroll
            for (int mt = 0; mt < 4; ++mt)
#pragma unroll
                for (int nt = 0; nt < 2; ++nt)
                    acc[mt][nt] = mfma16(af[mt][kk], bf[nt][kk], acc[mt][nt]);
        __builtin_amdgcn_s_setprio(0);
        __builtin_amdgcn_sched_barrier(0);
        __builtin_amdgcn_s_barrier();
        __builtin_amdgcn_sched_barrier(0);

#pragma unroll
        for (int nt = 0; nt < 2; ++nt)
#pragma unroll
            for (int kk = 0; kk < 2; ++kk)
                bf[nt][kk] = *(const short8*)&Bsb[(wn + (nt + 2) * 16 + tx) * 64 + sl[kk]];
        if (pf) { STG_A(nb, 2, t + 2) STG_A(nb, 3, t + 2) STG_B(nb, 1, t + 2) }
        __builtin_amdgcn_s_setprio(1);
#pragma unroll
        for (int kk = 0; kk < 2; ++kk)
#pragma unroll
            for (int mt = 0; mt < 4; ++mt)
#pragma unroll
                for (int nt = 0; nt < 2; ++nt)
                    acc[mt][nt + 2] = mfma16(af[mt][kk], bf[nt][kk], acc[mt][nt + 2]);
        __builtin_amdgcn_s_setprio(0);
        cb = (cb == 2) ? 0 : cb + 1;
    }

#pragma unroll
    for (int mt = 0; mt < 4; ++mt)
#pragma unroll
        for (int nt = 0; nt < 4; ++nt)
#pragma unroll
            for (int rg = 0; rg < 4; ++rg) {
                int m = bm + wm + mt * 16 + quad * 4 + rg;
                C[(size_t)m * 2048 + bn + wn + nt * 16 + tx] = acc[mt][nt][rg];
            }
}

// ---------------------------------------------------------------------------
// MFMA flash attention (R5, unchanged): 32x32x16, register-resident P,
// complementary tile pair (p, 31-p), reg-staged dbuf, 1 barrier/tile,
// builtin exp2, permlane32_swap, k-strip LDS combine.
// ---------------------------------------------------------------------------
__global__ __launch_bounds__(256, 4) void attn_mfma(
    const unsigned short* __restrict__ Q, const unsigned short* __restrict__ K,
    const unsigned short* __restrict__ Vt, unsigned short* __restrict__ O)
{
    __shared__ __align__(16) unsigned short smem[2][2][64 * 72];  // [buf][K|V]
    const int tid = threadIdx.x;
    const int lane = tid & 63, wq = tid >> 6;
    const int l32 = lane & 31, half = lane >> 5;
    const int qh = wq & 1;                 // q 32-row half
    const int ts = wq >> 1;                // 32-k strip of each 64-k tile
    const int p = blockIdx.x;              // pair id 0..15
    const int h = blockIdx.y, b = blockIdx.z;
    const int kvh = h >> 2;

    const int srow = tid >> 3, sc8 = (tid & 7) * 8;
    const unsigned short* gkB = &K[(((size_t)b * S_ + srow) * NKV_ + kvh) * HD_ + sc8];
    const unsigned short* gvB = &Vt[(size_t)(kvh * 64 + srow) * 4096 + (size_t)b * 2048 + sc8];
    const int woff = srow * 72 + sc8;

    for (int ph = 0; ph < 2; ++ph) {
        const int T = ph ? (31 - p) : p;

        const int qrow = T * 64 + qh * 32 + l32;
        const unsigned short* Qr = &Q[(((size_t)b * S_ + qrow) * NH_ + h) * HD_];
        short8 qf[4];
#pragma unroll
        for (int s = 0; s < 4; ++s)
            qf[s] = *(const short8*)(Qr + s * 16 + half * 8);

        float la = 0.f, lb = 0.f, lc = 0.f, ld = 0.f;
        v16f o0 = (v16f)0.f, o1 = (v16f)0.f;

        uint4 kr0 = *(const uint4*)(gkB);
        uint4 kr1 = *(const uint4*)(gkB + 32 * (NKV_ * HD_));
        uint4 vr0 = *(const uint4*)(gvB);
        uint4 vr1 = *(const uint4*)(gvB + (size_t)32 * 4096);
        int cur = 0;

        for (int kt = 0; kt <= T; ++kt) {
            unsigned short* Kw = &smem[cur][0][woff];
            unsigned short* Vw = &smem[cur][1][woff];
            *(uint4*)(Kw)           = kr0;
            *(uint4*)(Kw + 32 * 72) = kr1;
            *(uint4*)(Vw)           = vr0;
            *(uint4*)(Vw + 32 * 72) = vr1;
            __syncthreads();
            if (kt < T) {
                const unsigned short* gk = gkB + (size_t)(kt + 1) * 64 * (NKV_ * HD_);
                const unsigned short* gv = gvB + (kt + 1) * 64;
                kr0 = *(const uint4*)(gk);
                kr1 = *(const uint4*)(gk + 32 * (NKV_ * HD_));
                vr0 = *(const uint4*)(gv);
                vr1 = *(const uint4*)(gv + (size_t)32 * 4096);
            }
            const unsigned short* Ksb = smem[cur][0];
            const unsigned short* Vsb = smem[cur][1];
            cur ^= 1;

            const bool diag = (kt == T);
            if (diag && ts > qh) continue;
            const bool part = diag && (ts == qh);

            const int kb = (ts * 32 + l32) * 72 + half * 8;
            v16f st = (v16f)(-MAXC);
            __builtin_amdgcn_s_setprio(1);
            st = mfma32(*(const short8*)&Ksb[kb],      qf[0], st);
            st = mfma32(*(const short8*)&Ksb[kb + 16], qf[1], st);
            st = mfma32(*(const short8*)&Ksb[kb + 32], qf[2], st);
            st = mfma32(*(const short8*)&Ksb[kb + 48], qf[3], st);
            __builtin_amdgcn_s_setprio(0);

            float pv[16];
#pragma unroll
            for (int r = 0; r < 16; ++r) pv[r] = fexp2(st[r]);
            if (part) {
#pragma unroll
                for (int r = 0; r < 16; ++r) {
                    int krow = (r & 3) + 8 * (r >> 2) + 4 * half;
                    if (krow > l32) pv[r] = 0.f;
                }
            }
            la += (pv[0]  + pv[1])  + (pv[2]  + pv[3]);
            lb += (pv[4]  + pv[5])  + (pv[6]  + pv[7]);
            lc += (pv[8]  + pv[9])  + (pv[10] + pv[11]);
            ld += (pv[12] + pv[13]) + (pv[14] + pv[15]);

            unsigned int u[8];
#pragma unroll
            for (int g = 0; g < 4; ++g) {
                u[2 * g]     = pkbf(pv[4 * g],     pv[4 * g + 1]);
                u[2 * g + 1] = pkbf(pv[4 * g + 2], pv[4 * g + 3]);
            }
#pragma unroll
            for (int sg = 0; sg < 2; ++sg) {
                unsigned int a0 = u[4 * sg], a1 = u[4 * sg + 1];
                unsigned int b0 = u[4 * sg + 2], b1 = u[4 * sg + 3];
                uint4 fw;
#if __has_builtin(__builtin_amdgcn_permlane32_swap)
                typedef unsigned int u2v __attribute__((ext_vector_type(2)));
                u2v r0 = __builtin_amdgcn_permlane32_swap(a0, b0, false, false);
                u2v r1 = __builtin_amdgcn_permlane32_swap(a1, b1, false, false);
                fw.x = r0[0]; fw.y = r1[0]; fw.z = r0[1]; fw.w = r1[1];
#else
                unsigned int s0 = __shfl_xor((int)a0, 32);
                unsigned int s1 = __shfl_xor((int)a1, 32);
                unsigned int s2 = __shfl_xor((int)b0, 32);
                unsigned int s3 = __shfl_xor((int)b1, 32);
                fw.x = half ? s2 : a0;
                fw.y = half ? s3 : a1;
                fw.z = half ? b0 : s0;
                fw.w = half ? b1 : s1;
#endif
                short8 pf = *(short8*)&fw;
                const int vo = (2 * ts + sg) * 16 + half * 8;
                __builtin_amdgcn_s_setprio(1);
                o0 = mfma32(*(const short8*)&Vsb[l32 * 72 + vo],        pf, o0);
                o1 = mfma32(*(const short8*)&Vsb[(32 + l32) * 72 + vo], pf, o1);
                __builtin_amdgcn_s_setprio(0);
            }
        }

        float l = (la + lb) + (lc + ld);
        l += __shfl_xor(l, 32);

        __syncthreads();
        float* red = (float*)&smem[0][0][0];
        const int rbase = (qh * 64 + lane) * 33;
        if (ts == 1) {
#pragma unroll
            for (int r = 0; r < 16; ++r) { red[rbase + r] = o0[r]; red[rbase + 16 + r] = o1[r]; }
            red[rbase + 32] = l;
        }
        __syncthreads();
        if (ts == 0) {
#pragma unroll
            for (int r = 0; r < 16; ++r) { o0[r] += red[rbase + r]; o1[r] += red[rbase + 16 + r]; }
            l += red[rbase + 32];
            float inv = 1.f / l;
            int qg = T * 64 + qh * 32 + l32;
            unsigned short* orow = &O[((size_t)b * S_ + qg) * (NH_ * HD_) + h * HD_];
#pragma unroll
            for (int td = 0; td < 2; ++td) {
                const v16f& oo = td ? o1 : o0;
#pragma unroll
                for (int g = 0; g < 4; ++g) {
                    int d = td * 32 + g * 8 + half * 4;
                    uint2 uu;
                    uu.x = pkbf(oo[4 * g] * inv,     oo[4 * g + 1] * inv);
                    uu.y = pkbf(oo[4 * g + 2] * inv, oo[4 * g + 3] * inv);
                    *(uint2*)&orow[d] = uu;
                }
            }
        }
        if (ph == 0) __syncthreads();
    }
}

// ---------------------------------------------------------------------------
extern "C" void kernel_launch(void* const* d_in, const int* in_sizes, int n_in,
                              void* d_out, int out_size, void* d_ws, size_t ws_size,
                              hipStream_t stream)
{
    const float* x  = (const float*)d_in[0];
    const float* fc = (const float*)d_in[1];
    const float* fs = (const float*)d_in[2];
    // d_in[3] = mask: causal, applied structurally
    const float* Wq = (const float*)d_in[4];
    const float* bq = (const float*)d_in[5];
    const float* Wk = (const float*)d_in[6];
    const float* bk = (const float*)d_in[7];
    const float* Wv = (const float*)d_in[8];
    const float* bv = (const float*)d_in[9];
    const float* Wo = (const float*)d_in[10];
    float* out = (float*)d_out;

    unsigned short* ws = (unsigned short*)d_ws;
    unsigned short* xb  = ws;                  // 8388608
    unsigned short* wqb = ws + 8388608;        // 4194304
    unsigned short* wkb = ws + 12582912;       // 1048576
    unsigned short* wvb = ws + 13631488;       // 1048576
    unsigned short* wob = ws + 14680064;       // 4194304
    unsigned short* Qb  = ws + 18874368;       // 8388608
    unsigned short* Kb  = ws + 27262976;       // 2097152
    unsigned short* Vt  = ws + 29360128;       // 2097152
    unsigned short* Ob  = ws + 31457280;       // 8388608

    dim3 blk(256);
    convert_all<<<18432, blk, 0, stream>>>(x, Wq, Wk, Wv, Wo, xb, wqb, wkb, wvb, wob);
    qkv_gemm<<<192, dim3(512), 0, stream>>>(xb, wqb, wkb, wvb, bq, bk, bv,
                                            fc, fs, Qb, Kb, Vt);
    attn_mfma<<<dim3(16, NH_, B_), blk, 0, stream>>>(Qb, Kb, Vt, Ob);
    out_gemm<<<256, dim3(512), 0, stream>>>(Ob, wob, out);
}

// Round 9
// 299.149 us; speedup vs baseline: 1.0136x; 1.0136x over previous
//
#include <hip/hip_runtime.h>
#include <hip/hip_bf16.h>
#include <cstddef>
#include <cstdint>

#define B_   2
#define S_   2048
#define H_   2048
#define NH_  32
#define NKV_ 8
#define HD_  64

typedef __attribute__((ext_vector_type(8))) short short8;
typedef __attribute__((ext_vector_type(4))) float v4f;
typedef __attribute__((ext_vector_type(16))) float v16f;

#define MAXC 48.0f
#define QSCALE 0.18033688011112042f   /* 0.125 * log2(e) */

__device__ __forceinline__ unsigned short f2b(float f) {
    unsigned int u = __float_as_uint(f);
    u += 0x7FFFu + ((u >> 16) & 1u);
    return (unsigned short)(u >> 16);
}
__device__ __forceinline__ unsigned int pkbf(float a, float b) {
    __hip_bfloat162 h = __float22bfloat162_rn(float2{a, b});
    return *(unsigned int*)&h;
}
__device__ __forceinline__ float fexp2(float x) {
#if __has_builtin(__builtin_amdgcn_exp2f)
    return __builtin_amdgcn_exp2f(x);      // raw v_exp_f32; inputs in [-96, 0]
#else
    return exp2f(x);
#endif
}
__device__ __forceinline__ v4f mfma16(short8 a, short8 b, v4f c) {
    return __builtin_amdgcn_mfma_f32_16x16x32_bf16(a, b, c, 0, 0, 0);
}
__device__ __forceinline__ v16f mfma32(short8 a, short8 b, v16f c) {
    return __builtin_amdgcn_mfma_f32_32x32x16_bf16(a, b, c, 0, 0, 0);
}
__device__ __forceinline__ void gll16(void* lds, const void* g) {
    __builtin_amdgcn_global_load_lds(
        (const __attribute__((address_space(1))) unsigned int*)g,
        (__attribute__((address_space(3))) unsigned int*)lds, 16, 0, 0);
}

// ---------------------------------------------------------------------------
// fp32 -> bf16 conversion for x, Wq, Wk, Wv, Wo
// ---------------------------------------------------------------------------
__global__ __launch_bounds__(256) void convert_all(
    const float* __restrict__ x, const float* __restrict__ wq,
    const float* __restrict__ wk, const float* __restrict__ wv,
    const float* __restrict__ wo,
    unsigned short* __restrict__ xb, unsigned short* __restrict__ wqb,
    unsigned short* __restrict__ wkb, unsigned short* __restrict__ wvb,
    unsigned short* __restrict__ wob)
{
    size_t i = ((size_t)blockIdx.x * 256 + threadIdx.x) * 4;
    const float* src; unsigned short* dst; size_t off;
    if (i < 8388608)       { src = x;  dst = xb;  off = i; }
    else if (i < 12582912) { src = wq; dst = wqb; off = i - 8388608; }
    else if (i < 13631488) { src = wk; dst = wkb; off = i - 12582912; }
    else if (i < 14680064) { src = wv; dst = wvb; off = i - 13631488; }
    else                   { src = wo; dst = wob; off = i - 14680064; }
    float4 v = *(const float4*)(src + off);
    ushort4 o;
    o.x = f2b(v.x); o.y = f2b(v.y); o.z = f2b(v.z); o.w = f2b(v.w);
    *(ushort4*)(dst + off) = o;
}

// ---------------------------------------------------------------------------
// R9 qkv GEMM: BM=BN=256, BK=64, 512 thr / 8 waves (2M x 4N), wave-tile
// 128x64 (acc[8][4]), 2-buffer LDS 128KB (1 blk/CU), 4 phases x 16 MFMA.
// R9 fix vs R8: ALL 8 staging lines of tile t+1 are issued in phases 0-1
// (R8 spread them to ph3, leaving the tile-top vmcnt(0) gate only ~1 phase
// of slack < load latency -> per-tile stall, the 39%-local limiter).
// Now issue-to-wait distance >= 2.5 phases (~1300 cyc) > worst-case HBM
// latency, so the gate is free (T4's actual mechanism).
// Quadrant order m0n01 -> m0n23 -> m1n23 -> m1n01 (af reload ph0/ph2,
// bf ph0/ph1/ph3). Raw s_barrier + sched_barrier(0); setprio around MFMA.
// Swizzle (proven 0-conflict): LDS slot c of row r = chunk c^(r&7);
// read slot ((kk*4+quad)^(tx&7))*8.
// Grid 192 = 16M x 12N (XCD-bijective 8x24): bj 0-7 Q (RoPE+QSCALE),
// 8-9 K (RoPE), 10-11 V (transposed Vt[d][m]).
// ---------------------------------------------------------------------------
__global__ __launch_bounds__(512, 2) void qkv_gemm(
    const unsigned short* __restrict__ xb,
    const unsigned short* __restrict__ wqb, const unsigned short* __restrict__ wkb,
    const unsigned short* __restrict__ wvb,
    const float* __restrict__ bq, const float* __restrict__ bk,
    const float* __restrict__ bv,
    const float* __restrict__ fc, const float* __restrict__ fs,
    unsigned short* __restrict__ Qb, unsigned short* __restrict__ Kb,
    unsigned short* __restrict__ Vt)
{
    __shared__ unsigned short As[2][256 * 64];
    __shared__ unsigned short Bs[2][256 * 64];
    const int tid = threadIdx.x;
    const int lane = tid & 63, w = tid >> 6;       // 8 waves
    const int tx = lane & 15, quad = lane >> 4;

    const int bid = blockIdx.x;                    // 192 = 8 XCD x 24
    const int swz = (bid & 7) * 24 + (bid >> 3);
    const int bi = swz / 12, bj = swz % 12;
    const int bm = bi * 256;

    const unsigned short* Bp; int mode, nbase;
    if (bj < 8)       { Bp = wqb + (size_t)(bj * 256) * 2048;        mode = 0; nbase = bj * 256; }
    else if (bj < 10) { Bp = wkb + (size_t)((bj - 8) * 256) * 2048;  mode = 1; nbase = (bj - 8) * 256; }
    else              { Bp = wvb + (size_t)((bj - 10) * 256) * 2048; mode = 2; nbase = (bj - 10) * 256; }
    const unsigned short* Ap = xb + (size_t)bm * 2048;

    const int wm = (w >> 2) * 128, wn = (w & 3) * 64;

    v4f acc[8][4];
#pragma unroll
    for (int i = 0; i < 8; ++i)
#pragma unroll
        for (int j = 0; j < 4; ++j) acc[i][j] = (v4f)0.f;

    // staging: wave w stages rows [w*32, w*32+32) per line-group; lane ->
    // row i*8+(lane>>3), global chunk (lane&7)^(lane>>3) of the 64-elem slab
    const int r8 = lane >> 3, gc = (lane & 7) ^ r8;
    const unsigned short* ga = Ap + (size_t)(w * 32 + r8) * 2048 + gc * 8;
    const unsigned short* gb = Bp + (size_t)(w * 32 + r8) * 2048 + gc * 8;

#define SA(c, i, t) gll16(&As[c][(w * 32 + (i) * 8) * 64], \
                          ga + (size_t)((i) * 8) * 2048 + (size_t)(t) * 64);
#define SB(c, i, t) gll16(&Bs[c][(w * 32 + (i) * 8) * 64], \
                          gb + (size_t)((i) * 8) * 2048 + (size_t)(t) * 64);

    // frag-read slots (loop-invariant): chunk kk*4+quad XOR (row&7 = tx&7)
    const int t7 = tx & 7;
    int sl[2];
#pragma unroll
    for (int kk = 0; kk < 2; ++kk) sl[kk] = ((kk * 4 + quad) ^ t7) * 8;

    // prologue: tile 0 -> buf0
    SA(0, 0, 0) SA(0, 1, 0) SA(0, 2, 0) SA(0, 3, 0)
    SB(0, 0, 0) SB(0, 1, 0) SB(0, 2, 0) SB(0, 3, 0)

    short8 af[4][2], bf[2][2];

    for (int t = 0; t < 32; ++t) {
        const int cur = t & 1, nxt = cur ^ 1;
        asm volatile("s_waitcnt vmcnt(0)" ::: "memory");
        __builtin_amdgcn_sched_barrier(0);
        __builtin_amdgcn_s_barrier();              // tile t resident; buf nxt free
        __builtin_amdgcn_sched_barrier(0);
        const unsigned short* Asb = As[cur];
        const unsigned short* Bsb = Bs[cur];
        const bool pf = (t < 31);

        // ---- ph0: quadrant m0 x n01 ; stage A0,A1,B0,B1 of t+1 ----
#pragma unroll
        for (int mt = 0; mt < 4; ++mt)
#pragma unroll
            for (int kk = 0; kk < 2; ++kk)
                af[mt][kk] = *(const short8*)&Asb[(wm + mt * 16 + tx) * 64 + sl[kk]];
#pragma unroll
        for (int nt = 0; nt < 2; ++nt)
#pragma unroll
            for (int kk = 0; kk < 2; ++kk)
                bf[nt][kk] = *(const short8*)&Bsb[(wn + nt * 16 + tx) * 64 + sl[kk]];
        if (pf) { SA(nxt, 0, t + 1) SA(nxt, 1, t + 1) SB(nxt, 0, t + 1) SB(nxt, 1, t + 1) }
        __builtin_amdgcn_s_setprio(1);
#pragma unroll
        for (int kk = 0; kk < 2; ++kk)
#pragma unroll
            for (int mt = 0; mt < 4; ++mt)
#pragma unroll
                for (int nt = 0; nt < 2; ++nt)
                    acc[mt][nt] = mfma16(af[mt][kk], bf[nt][kk], acc[mt][nt]);
        __builtin_amdgcn_s_setprio(0);
        __builtin_amdgcn_sched_barrier(0);
        __builtin_amdgcn_s_barrier();
        __builtin_amdgcn_sched_barrier(0);

        // ---- ph1: quadrant m0 x n23 ; stage A2,A3,B2,B3 of t+1 ----
#pragma unroll
        for (int nt = 0; nt < 2; ++nt)
#pragma unroll
            for (int kk = 0; kk < 2; ++kk)
                bf[nt][kk] = *(const short8*)&Bsb[(wn + (nt + 2) * 16 + tx) * 64 + sl[kk]];
        if (pf) { SA(nxt, 2, t + 1) SA(nxt, 3, t + 1) SB(nxt, 2, t + 1) SB(nxt, 3, t + 1) }
        __builtin_amdgcn_s_setprio(1);
#pragma unroll
        for (int kk = 0; kk < 2; ++kk)
#pragma unroll
            for (int mt = 0; mt < 4; ++mt)
#pragma unroll
                for (int nt = 0; nt < 2; ++nt)
                    acc[mt][nt + 2] = mfma16(af[mt][kk], bf[nt][kk], acc[mt][nt + 2]);
        __builtin_amdgcn_s_setprio(0);
        __builtin_amdgcn_sched_barrier(0);
        __builtin_amdgcn_s_barrier();
        __builtin_amdgcn_sched_barrier(0);

        // ---- ph2: quadrant m1 x n23 (reuse bf) ----
#pragma unroll
        for (int mt = 0; mt < 4; ++mt)
#pragma unroll
            for (int kk = 0; kk < 2; ++kk)
                af[mt][kk] = *(const short8*)&Asb[(wm + 64 + mt * 16 + tx) * 64 + sl[kk]];
        __builtin_amdgcn_s_setprio(1);
#pragma unroll
        for (int kk = 0; kk < 2; ++kk)
#pragma unroll
            for (int mt = 0; mt < 4; ++mt)
#pragma unroll
                for (int nt = 0; nt < 2; ++nt)
                    acc[mt + 4][nt + 2] = mfma16(af[mt][kk], bf[nt][kk], acc[mt + 4][nt + 2]);
        __builtin_amdgcn_s_setprio(0);
        __builtin_amdgcn_sched_barrier(0);
        __builtin_amdgcn_s_barrier();
        __builtin_amdgcn_sched_barrier(0);

        // ---- ph3: quadrant m1 x n01 ----
#pragma unroll
        for (int nt = 0; nt < 2; ++nt)
#pragma unroll
            for (int kk = 0; kk < 2; ++kk)
                bf[nt][kk] = *(const short8*)&Bsb[(wn + nt * 16 + tx) * 64 + sl[kk]];
        __builtin_amdgcn_s_setprio(1);
#pragma unroll
        for (int kk = 0; kk < 2; ++kk)
#pragma unroll
            for (int mt = 0; mt < 4; ++mt)
#pragma unroll
                for (int nt = 0; nt < 2; ++nt)
                    acc[mt + 4][nt] = mfma16(af[mt][kk], bf[nt][kk], acc[mt + 4][nt]);
        __builtin_amdgcn_s_setprio(0);
        // no trailing barrier: next tile's top barrier orders buffer reuse
    }
#undef SA
#undef SB

    if (mode <= 1) {
        unsigned short* Cout = mode ? Kb : Qb;
        const float* bias    = mode ? bk : bq;
        const int ldN        = mode ? 512 : 2048;
        const float scq      = mode ? 1.0f : QSCALE;
        float bx0 = bias[nbase + wn +  0 + tx];
        float bx1 = bias[nbase + wn + 16 + tx];
        float bx2 = bias[nbase + wn + 32 + tx];
        float bx3 = bias[nbase + wn + 48 + tx];
#pragma unroll
        for (int mt = 0; mt < 8; ++mt)
#pragma unroll
            for (int rg = 0; rg < 4; ++rg) {
                int m = bm + wm + mt * 16 + quad * 4 + rg;
                int s = m & (S_ - 1);
                float c0 = fc[s * 32 + tx],      c1 = fc[s * 32 + 16 + tx];
                float s0 = fs[s * 32 + tx],      s1 = fs[s * 32 + 16 + tx];
                float q0 = acc[mt][0][rg] + bx0, q1 = acc[mt][1][rg] + bx1;
                float q2 = acc[mt][2][rg] + bx2, q3 = acc[mt][3][rg] + bx3;
                size_t base = (size_t)m * ldN + nbase + wn + tx;
                Cout[base]      = f2b((q0 * c0 - q2 * s0) * scq);
                Cout[base + 16] = f2b((q1 * c1 - q3 * s1) * scq);
                Cout[base + 32] = f2b((q2 * c0 + q0 * s0) * scq);
                Cout[base + 48] = f2b((q3 * c1 + q1 * s1) * scq);
            }
    } else {
        // V: acc[m][d] -> Vt[d * 4096 + m] (m = b*2048 + s), 8B stores
#pragma unroll
        for (int nt = 0; nt < 4; ++nt) {
            int d = nbase + wn + nt * 16 + tx;
            float bvv = bv[d];
#pragma unroll
            for (int mt = 0; mt < 8; ++mt) {
                int m0 = bm + wm + mt * 16 + quad * 4;
                ushort4 o;
                o.x = f2b(acc[mt][nt][0] + bvv);
                o.y = f2b(acc[mt][nt][1] + bvv);
                o.z = f2b(acc[mt][nt][2] + bvv);
                o.w = f2b(acc[mt][nt][3] + bvv);
                *(ushort4*)&Vt[(size_t)d * 4096 + m0] = o;
            }
        }
    }
}

// staging helpers for out_gemm (R7 template)
#define STG_A(c, i, t) gll16(&As[c][(w * 32 + (i) * 8) * 64], \
                             ga + (size_t)((i) * 8) * 2048 + (size_t)(t) * 64);
#define STG_B(c, i, t) gll16(&Bs[c][(w * 16 + (i) * 8) * 64], \
                             gb + (size_t)((i) * 8) * 2048 + (size_t)(t) * 64);

// ---------------------------------------------------------------------------
// Output GEMM — R7 template unchanged (exact 256-block fill).
// ---------------------------------------------------------------------------
__global__ __launch_bounds__(512, 2) void out_gemm(
    const unsigned short* __restrict__ Ab, const unsigned short* __restrict__ Bw,
    float* __restrict__ C)
{
    __shared__ unsigned short As[3][256 * 64];
    __shared__ unsigned short Bs[3][128 * 64];
    const int tid = threadIdx.x;
    const int lane = tid & 63, w = tid >> 6;
    const int tx = lane & 15, quad = lane >> 4;

    const int bid = blockIdx.x;                    // 256 = 8 XCD x 32
    const int swz = (bid & 7) * 32 + (bid >> 3);
    const int bm = (swz >> 4) * 256, bn = (swz & 15) * 128;

    const int wm = (w >> 1) * 64, wn = (w & 1) * 64;

    v4f acc[4][4];
#pragma unroll
    for (int i = 0; i < 4; ++i)
#pragma unroll
        for (int j = 0; j < 4; ++j) acc[i][j] = (v4f)0.f;

    const int r8 = lane >> 3, gc = (lane & 7) ^ r8;
    const unsigned short* ga = Ab + (size_t)(bm + w * 32 + r8) * 2048 + gc * 8;
    const unsigned short* gb = Bw + (size_t)(bn + w * 16 + r8) * 2048 + gc * 8;

    const int t7 = tx & 7;
    int sl[2];
#pragma unroll
    for (int kk = 0; kk < 2; ++kk) sl[kk] = ((kk * 4 + quad) ^ t7) * 8;

    STG_A(0, 0, 0) STG_A(0, 1, 0) STG_B(0, 0, 0)
    STG_A(0, 2, 0) STG_A(0, 3, 0) STG_B(0, 1, 0)
    STG_A(1, 0, 1) STG_A(1, 1, 1) STG_B(1, 0, 1)
    STG_A(1, 2, 1) STG_A(1, 3, 1) STG_B(1, 1, 1)

    int cb = 0;
    for (int t = 0; t < 32; ++t) {
        if (t < 31) asm volatile("s_waitcnt vmcnt(6)" ::: "memory");
        else        asm volatile("s_waitcnt vmcnt(0)" ::: "memory");
        __builtin_amdgcn_sched_barrier(0);
        __builtin_amdgcn_s_barrier();
        __builtin_amdgcn_sched_barrier(0);

        const unsigned short* Asb = As[cb];
        const unsigned short* Bsb = Bs[cb];
        const int nb = (cb == 0) ? 2 : cb - 1;
        const bool pf = (t < 30);

        short8 af[4][2], bf[2][2];
#pragma unroll
        for (int mt = 0; mt < 4; ++mt)
#pragma unroll
            for (int kk = 0; kk < 2; ++kk)
                af[mt][kk] = *(const short8*)&Asb[(wm + mt * 16 + tx) * 64 + sl[kk]];
#pragma unroll
        for (int nt = 0; nt < 2; ++nt)
#pragma unroll
            for (int kk = 0; kk < 2; ++kk)
                bf[nt][kk] = *(const short8*)&Bsb[(wn + nt * 16 + tx) * 64 + sl[kk]];
        if (pf) { STG_A(nb, 0, t + 2) STG_A(nb, 1, t + 2) STG_B(nb, 0, t + 2) }
        __builtin_amdgcn_s_setprio(1);
#pragma unroll
        for (int kk = 0; kk < 2; ++kk)
#pragma unroll
            for (int mt = 0; mt < 4; ++mt)
#pragma unroll
                for (int nt = 0; nt < 2; ++nt)
                    acc[mt][nt] = mfma16(af[mt][kk], bf[nt][kk], acc[mt][nt]);
        __builtin_amdgcn_s_setprio(0);
        __builtin_amdgcn_sched_barrier(0);
        __builtin_amdgcn_s_barrier();
        __builtin_amdgcn_sched_barrier(0);

#pragma unroll
        for (int nt = 0; nt < 2; ++nt)
#pragma unroll
            for (int kk = 0; kk < 2; ++kk)
                bf[nt][kk] = *(const short8*)&Bsb[(wn + (nt + 2) * 16 + tx) * 64 + sl[kk]];
        if (pf) { STG_A(nb, 2, t + 2) STG_A(nb, 3, t + 2) STG_B(nb, 1, t + 2) }
        __builtin_amdgcn_s_setprio(1);
#pragma unroll
        for (int kk = 0; kk < 2; ++kk)
#pragma unroll
            for (int mt = 0; mt < 4; ++mt)
#pragma unroll
                for (int nt = 0; nt < 2; ++nt)
                    acc[mt][nt + 2] = mfma16(af[mt][kk], bf[nt][kk], acc[mt][nt + 2]);
        __builtin_amdgcn_s_setprio(0);
        cb = (cb == 2) ? 0 : cb + 1;
    }

#pragma unroll
    for (int mt = 0; mt < 4; ++mt)
#pragma unroll
        for (int nt = 0; nt < 4; ++nt)
#pragma unroll
            for (int rg = 0; rg < 4; ++rg) {
                int m = bm + wm + mt * 16 + quad * 4 + rg;
                C[(size_t)m * 2048 + bn + wn + nt * 16 + tx] = acc[mt][nt][rg];
            }
}

// ---------------------------------------------------------------------------
// MFMA flash attention (R5, unchanged): 32x32x16, register-resident P,
// complementary tile pair (p, 31-p), reg-staged dbuf, 1 barrier/tile,
// builtin exp2, permlane32_swap, k-strip LDS combine.
// ---------------------------------------------------------------------------
__global__ __launch_bounds__(256, 4) void attn_mfma(
    const unsigned short* __restrict__ Q, const unsigned short* __restrict__ K,
    const unsigned short* __restrict__ Vt, unsigned short* __restrict__ O)
{
    __shared__ __align__(16) unsigned short smem[2][2][64 * 72];  // [buf][K|V]
    const int tid = threadIdx.x;
    const int lane = tid & 63, wq = tid >> 6;
    const int l32 = lane & 31, half = lane >> 5;
    const int qh = wq & 1;                 // q 32-row half
    const int ts = wq >> 1;                // 32-k strip of each 64-k tile
    const int p = blockIdx.x;              // pair id 0..15
    const int h = blockIdx.y, b = blockIdx.z;
    const int kvh = h >> 2;

    const int srow = tid >> 3, sc8 = (tid & 7) * 8;
    const unsigned short* gkB = &K[(((size_t)b * S_ + srow) * NKV_ + kvh) * HD_ + sc8];
    const unsigned short* gvB = &Vt[(size_t)(kvh * 64 + srow) * 4096 + (size_t)b * 2048 + sc8];
    const int woff = srow * 72 + sc8;

    for (int ph = 0; ph < 2; ++ph) {
        const int T = ph ? (31 - p) : p;

        const int qrow = T * 64 + qh * 32 + l32;
        const unsigned short* Qr = &Q[(((size_t)b * S_ + qrow) * NH_ + h) * HD_];
        short8 qf[4];
#pragma unroll
        for (int s = 0; s < 4; ++s)
            qf[s] = *(const short8*)(Qr + s * 16 + half * 8);

        float la = 0.f, lb = 0.f, lc = 0.f, ld = 0.f;
        v16f o0 = (v16f)0.f, o1 = (v16f)0.f;

        uint4 kr0 = *(const uint4*)(gkB);
        uint4 kr1 = *(const uint4*)(gkB + 32 * (NKV_ * HD_));
        uint4 vr0 = *(const uint4*)(gvB);
        uint4 vr1 = *(const uint4*)(gvB + (size_t)32 * 4096);
        int cur = 0;

        for (int kt = 0; kt <= T; ++kt) {
            unsigned short* Kw = &smem[cur][0][woff];
            unsigned short* Vw = &smem[cur][1][woff];
            *(uint4*)(Kw)           = kr0;
            *(uint4*)(Kw + 32 * 72) = kr1;
            *(uint4*)(Vw)           = vr0;
            *(uint4*)(Vw + 32 * 72) = vr1;
            __syncthreads();
            if (kt < T) {
                const unsigned short* gk = gkB + (size_t)(kt + 1) * 64 * (NKV_ * HD_);
                const unsigned short* gv = gvB + (kt + 1) * 64;
                kr0 = *(const uint4*)(gk);
                kr1 = *(const uint4*)(gk + 32 * (NKV_ * HD_));
                vr0 = *(const uint4*)(gv);
                vr1 = *(const uint4*)(gv + (size_t)32 * 4096);
            }
            const unsigned short* Ksb = smem[cur][0];
            const unsigned short* Vsb = smem[cur][1];
            cur ^= 1;

            const bool diag = (kt == T);
            if (diag && ts > qh) continue;
            const bool part = diag && (ts == qh);

            const int kb = (ts * 32 + l32) * 72 + half * 8;
            v16f st = (v16f)(-MAXC);
            __builtin_amdgcn_s_setprio(1);
            st = mfma32(*(const short8*)&Ksb[kb],      qf[0], st);
            st = mfma32(*(const short8*)&Ksb[kb + 16], qf[1], st);
            st = mfma32(*(const short8*)&Ksb[kb + 32], qf[2], st);
            st = mfma32(*(const short8*)&Ksb[kb + 48], qf[3], st);
            __builtin_amdgcn_s_setprio(0);

            float pv[16];
#pragma unroll
            for (int r = 0; r < 16; ++r) pv[r] = fexp2(st[r]);
            if (part) {
#pragma unroll
                for (int r = 0; r < 16; ++r) {
                    int krow = (r & 3) + 8 * (r >> 2) + 4 * half;
                    if (krow > l32) pv[r] = 0.f;
                }
            }
            la += (pv[0]  + pv[1])  + (pv[2]  + pv[3]);
            lb += (pv[4]  + pv[5])  + (pv[6]  + pv[7]);
            lc += (pv[8]  + pv[9])  + (pv[10] + pv[11]);
            ld += (pv[12] + pv[13]) + (pv[14] + pv[15]);

            unsigned int u[8];
#pragma unroll
            for (int g = 0; g < 4; ++g) {
                u[2 * g]     = pkbf(pv[4 * g],     pv[4 * g + 1]);
                u[2 * g + 1] = pkbf(pv[4 * g + 2], pv[4 * g + 3]);
            }
#pragma unroll
            for (int sg = 0; sg < 2; ++sg) {
                unsigned int a0 = u[4 * sg], a1 = u[4 * sg + 1];
                unsigned int b0 = u[4 * sg + 2], b1 = u[4 * sg + 3];
                uint4 fw;
#if __has_builtin(__builtin_amdgcn_permlane32_swap)
                typedef unsigned int u2v __attribute__((ext_vector_type(2)));
                u2v r0 = __builtin_amdgcn_permlane32_swap(a0, b0, false, false);
                u2v r1 = __builtin_amdgcn_permlane32_swap(a1, b1, false, false);
                fw.x = r0[0]; fw.y = r1[0]; fw.z = r0[1]; fw.w = r1[1];
#else
                unsigned int s0 = __shfl_xor((int)a0, 32);
                unsigned int s1 = __shfl_xor((int)a1, 32);
                unsigned int s2 = __shfl_xor((int)b0, 32);
                unsigned int s3 = __shfl_xor((int)b1, 32);
                fw.x = half ? s2 : a0;
                fw.y = half ? s3 : a1;
                fw.z = half ? b0 : s0;
                fw.w = half ? b1 : s1;
#endif
                short8 pf = *(short8*)&fw;
                const int vo = (2 * ts + sg) * 16 + half * 8;
                __builtin_amdgcn_s_setprio(1);
                o0 = mfma32(*(const short8*)&Vsb[l32 * 72 + vo],        pf, o0);
                o1 = mfma32(*(const short8*)&Vsb[(32 + l32) * 72 + vo], pf, o1);
                __builtin_amdgcn_s_setprio(0);
            }
        }

        float l = (la + lb) + (lc + ld);
        l += __shfl_xor(l, 32);

        __syncthreads();
        float* red = (float*)&smem[0][0][0];
        const int rbase = (qh * 64 + lane) * 33;
        if (ts == 1) {
#pragma unroll
            for (int r = 0; r < 16; ++r) { red[rbase + r] = o0[r]; red[rbase + 16 + r] = o1[r]; }
            red[rbase + 32] = l;
        }
        __syncthreads();
        if (ts == 0) {
#pragma unroll
            for (int r = 0; r < 16; ++r) { o0[r] += red[rbase + r]; o1[r] += red[rbase + 16 + r]; }
            l += red[rbase + 32];
            float inv = 1.f / l;
            int qg = T * 64 + qh * 32 + l32;
            unsigned short* orow = &O[((size_t)b * S_ + qg) * (NH_ * HD_) + h * HD_];
#pragma unroll
            for (int td = 0; td < 2; ++td) {
                const v16f& oo = td ? o1 : o0;
#pragma unroll
                for (int g = 0; g < 4; ++g) {
                    int d = td * 32 + g * 8 + half * 4;
                    uint2 uu;
                    uu.x = pkbf(oo[4 * g] * inv,     oo[4 * g + 1] * inv);
                    uu.y = pkbf(oo[4 * g + 2] * inv, oo[4 * g + 3] * inv);
                    *(uint2*)&orow[d] = uu;
                }
            }
        }
        if (ph == 0) __syncthreads();
    }
}

// ---------------------------------------------------------------------------
extern "C" void kernel_launch(void* const* d_in, const int* in_sizes, int n_in,
                              void* d_out, int out_size, void* d_ws, size_t ws_size,
                              hipStream_t stream)
{
    const float* x  = (const float*)d_in[0];
    const float* fc = (const float*)d_in[1];
    const float* fs = (const float*)d_in[2];
    // d_in[3] = mask: causal, applied structurally
    const float* Wq = (const float*)d_in[4];
    const float* bq = (const float*)d_in[5];
    const float* Wk = (const float*)d_in[6];
    const float* bk = (const float*)d_in[7];
    const float* Wv = (const float*)d_in[8];
    const float* bv = (const float*)d_in[9];
    const float* Wo = (const float*)d_in[10];
    float* out = (float*)d_out;

    unsigned short* ws = (unsigned short*)d_ws;
    unsigned short* xb  = ws;                  // 8388608
    unsigned short* wqb = ws + 8388608;        // 4194304
    unsigned short* wkb = ws + 12582912;       // 1048576
    unsigned short* wvb = ws + 13631488;       // 1048576
    unsigned short* wob = ws + 14680064;       // 4194304
    unsigned short* Qb  = ws + 18874368;       // 8388608
    unsigned short* Kb  = ws + 27262976;       // 2097152
    unsigned short* Vt  = ws + 29360128;       // 2097152
    unsigned short* Ob  = ws + 31457280;       // 8388608

    dim3 blk(256);
    convert_all<<<18432, blk, 0, stream>>>(x, Wq, Wk, Wv, Wo, xb, wqb, wkb, wvb, wob);
    qkv_gemm<<<192, dim3(512), 0, stream>>>(xb, wqb, wkb, wvb, bq, bk, bv,
                                            fc, fs, Qb, Kb, Vt);
    attn_mfma<<<dim3(16, NH_, B_), blk, 0, stream>>>(Qb, Kb, Vt, Ob);
    out_gemm<<<256, dim3(512), 0, stream>>>(Ob, wob, out);
}